// Round 9
// baseline (1065.677 us; speedup 1.0000x reference)
//
#include <hip/hip_runtime.h>

typedef unsigned short u16;   // raw bf16 bits (INTERNAL storage only)
typedef __attribute__((ext_vector_type(4))) float f32x4;
typedef __attribute__((ext_vector_type(2))) float f32x2;
typedef __attribute__((ext_vector_type(8))) short bf16x8;

constexpr int Nn  = 50000;
constexpr int Ee  = 500000;
constexpr int ET  = Nn + Ee;      // edges incl. self-loops
constexpr int FIN = 128;
constexpr int FE  = 16;
constexpr int Hh  = 8;
constexpr int C1  = 32, HC1 = 256;
constexpr int C2  = 16, HC2 = 128;
constexpr float NS  = 0.2f;
constexpr float EPS = 1e-5f;
constexpr float LOG2E = 1.44269504088896340736f;

__device__ __forceinline__ float b2f(u16 u) { return __uint_as_float(((unsigned)u) << 16); }
__device__ __forceinline__ u16 f2b(float f) {
  unsigned u = __float_as_uint(f);
  u += 0x7FFF + ((u >> 16) & 1);          // round-to-nearest-even
  return (u16)(u >> 16);
}

// ---- packed-f32 VOP3P helpers (encoding HW-verified by R6's passing run) ----
// acc += {s.lo, s.lo} * w   (broadcast LOW scalar of pair s)
__device__ __forceinline__ f32x2 pk_fma_lo(f32x2 s, f32x2 w, f32x2 acc) {
  asm("v_pk_fma_f32 %0, %1, %2, %0 op_sel:[0,0,0] op_sel_hi:[0,1,1]"
      : "+v"(acc) : "v"(s), "v"(w));
  return acc;
}
// acc += {s.hi, s.hi} * w   (broadcast HIGH scalar of pair s)
__device__ __forceinline__ f32x2 pk_fma_hi(f32x2 s, f32x2 w, f32x2 acc) {
  asm("v_pk_fma_f32 %0, %1, %2, %0 op_sel:[1,0,0] op_sel_hi:[1,1,1]"
      : "+v"(acc) : "v"(s), "v"(w));
  return acc;
}

// DPP butterfly sum over RED lanes (RED = 8 or 16). VALU-only: no lgkmcnt.
template <int RED>
__device__ __forceinline__ float red_sum(float v) {
  v += __int_as_float(__builtin_amdgcn_update_dpp(0, __float_as_int(v), 0xB1, 0xF, 0xF, true));
  v += __int_as_float(__builtin_amdgcn_update_dpp(0, __float_as_int(v), 0x4E, 0xF, 0xF, true));
  v += __int_as_float(__builtin_amdgcn_update_dpp(0, __float_as_int(v), 0x141, 0xF, 0xF, true));
  if constexpr (RED == 16)
    v += __int_as_float(__builtin_amdgcn_update_dpp(0, __float_as_int(v), 0x140, 0xF, 0xF, true));
  return v;
}

// ---------------- init ----
__global__ void k_init(int* __restrict__ deg, int* __restrict__ cursor, float* __restrict__ ea_mean,
                       float* __restrict__ bn1s, float* __restrict__ bn1q,
                       float* __restrict__ bn2s, float* __restrict__ bn2q) {
  int t = blockIdx.x * 256 + threadIdx.x;
  int stride = gridDim.x * 256;
  for (int i = t; i < Nn; i += stride) { deg[i] = 0; cursor[i] = 0; }
  if (t < FE) ea_mean[t] = 0.f;
  if (t >= 64 && t < 64 + HC1) { bn1s[t - 64] = 0.f; bn1q[t - 64] = 0.f; }
  if (t >= 384 && t < 384 + HC2) { bn2s[t - 384] = 0.f; bn2q[t - 384] = 0.f; }
}

// ---------------- degree histogram + edge_attr mean ----
__global__ void k_deg_mean(const int* __restrict__ ei, const float* __restrict__ ea,
                           int* __restrict__ deg, float* __restrict__ ea_mean) {
  int t = threadIdx.x;
  int e = blockIdx.x * 256 + t;
  if (e < ET) {
    int d = (e < Ee) ? ei[Ee + e] : (e - Ee);
    if ((unsigned)d >= (unsigned)Nn) d = 0;   // safety clamp
    atomicAdd(&deg[d], 1);
  }
  __shared__ float s[256];
  int f  = t & 15;
  int r0 = (t >> 4) + blockIdx.x * 16;
  float acc = 0.f;
  for (int r = r0; r < Ee; r += gridDim.x * 16) acc += ea[r * FE + f];
  s[t] = acc;
  __syncthreads();
  if (t < 16) {
    float v = 0.f;
    for (int r = 0; r < 16; r++) v += s[r * 16 + t];
    atomicAdd(&ea_mean[t], v * (1.f / Ee));
  }
}

__global__ __launch_bounds__(1024) void k_scan(const int* __restrict__ deg, int* __restrict__ rowptr) {
  const int T = 1024;
  int t = threadIdx.x;
  const int CH = (Nn + T - 1) / T;  // 49
  int base = t * CH;
  int sum = 0;
  for (int i = 0; i < CH; i++) {
    int idx = base + i;
    if (idx < Nn) sum += deg[idx];
  }
  __shared__ int s[T];
  s[t] = sum;
  __syncthreads();
  for (int off = 1; off < T; off <<= 1) {
    int v = (t >= off) ? s[t - off] : 0;
    __syncthreads();
    s[t] += v;
    __syncthreads();
  }
  int run = (t == 0) ? 0 : s[t - 1];
  for (int i = 0; i < CH; i++) {
    int idx = base + i;
    if (idx < Nn) { rowptr[idx] = run; run += deg[idx]; }
  }
  if (t == T - 1) rowptr[Nn] = run;  // == ET
}

// scatter (dst-sorted); pads epack[ET..ET+3] so the attn kernel needs no clamps
__global__ void k_scatter(const int* __restrict__ ei, const int* __restrict__ rowptr,
                          int* __restrict__ cursor, int2* __restrict__ epack) {
  int e = blockIdx.x * 256 + threadIdx.x;
  if (e >= ET) return;
  if (e < 4) epack[ET + e] = make_int2(0, Ee);    // pad: s=0 (safe gather), eid=Ee (mean path)
  int s, d;
  if (e < Ee) { s = ei[e]; d = ei[Ee + e]; } else { s = d = e - Ee; }
  if ((unsigned)s >= (unsigned)Nn) s = 0;   // safety clamp
  if ((unsigned)d >= (unsigned)Nn) d = 0;
  int pos = rowptr[d] + atomicAdd(&cursor[d], 1);
  epack[pos] = make_int2(s, e);
}

// ---------------- BN coefficients ----------------
__global__ void k_bn_coef(const float* __restrict__ sum, const float* __restrict__ sq,
                          const float* __restrict__ g, const float* __restrict__ bt,
                          float2* __restrict__ coef, int HC) {
  int ch = threadIdx.x;
  if (ch >= HC) return;
  float mu = sum[ch] * (1.f / Nn);
  float var = sq[ch] * (1.f / Nn) - mu * mu;
  float rs = rsqrtf(var + EPS);
  float sc = g[ch] * rs;
  coef[ch] = make_float2(sc, bt[ch] - sc * mu);
}

// ------- MFMA bf16 GEMM -------
template <int KK, int NN, typename AT, bool FUSE>
__global__ __launch_bounds__(256) void k_gemm_mfma(const AT* __restrict__ A, const float* __restrict__ W,
                                                   const float* __restrict__ bias, u16* __restrict__ C,
                                                   const float2* __restrict__ coef, int M) {
  constexpr int WT = KK + 8;
  __shared__ u16 Wt[64 * WT];
  int tid = threadIdx.x;
  int col0 = blockIdx.x * 64;
  int row0 = blockIdx.y * 64;
  for (int idx = tid; idx < KK * 64; idx += 256) {   // stage W -> LDS (transposed, bf16)
    int k = idx >> 6, c = idx & 63;
    Wt[c * WT + k] = f2b(W[(size_t)k * NN + col0 + c]);
  }
  __syncthreads();
  int lane = tid & 63;
  int w = tid >> 6;
  int mr = lane & 15, quad = lane >> 4;
  int row = row0 + w * 16 + mr;
  f32x4 acc[4];
#pragma unroll
  for (int t = 0; t < 4; t++) acc[t] = (f32x4){0.f, 0.f, 0.f, 0.f};
  union Frag { bf16x8 v; u16 u[8]; };
  for (int kb = 0; kb < KK; kb += 32) {
    Frag a;
    if (row < M) {
      if constexpr (sizeof(AT) == 4) {               // fp32 input -> convert
        const float* ap = (const float*)&A[(size_t)row * KK + kb + quad * 8];
        float4 a0 = *reinterpret_cast<const float4*>(ap);
        float4 a1 = *reinterpret_cast<const float4*>(ap + 4);
        a.u[0] = f2b(a0.x); a.u[1] = f2b(a0.y); a.u[2] = f2b(a0.z); a.u[3] = f2b(a0.w);
        a.u[4] = f2b(a1.x); a.u[5] = f2b(a1.y); a.u[6] = f2b(a1.z); a.u[7] = f2b(a1.w);
      } else {                                       // bf16 internal
        a.v = *reinterpret_cast<const bf16x8*>(&A[(size_t)row * KK + kb + quad * 8]);
        if constexpr (FUSE) {
          int k0 = kb + quad * 8;
#pragma unroll
          for (int j = 0; j < 8; j++) {
            float2 c2 = coef[k0 + j];
            float y = b2f(a.u[j]) * c2.x + c2.y;
            y = y > 0.f ? y : __expf(y) - 1.f;       // ELU
            a.u[j] = f2b(y);
          }
        }
      }
    } else {
#pragma unroll
      for (int j = 0; j < 8; j++) a.u[j] = 0;
    }
#pragma unroll
    for (int t = 0; t < 4; t++) {
      const bf16x8* bp = reinterpret_cast<const bf16x8*>(&Wt[(t * 16 + mr) * WT + kb + quad * 8]);
      acc[t] = __builtin_amdgcn_mfma_f32_16x16x32_bf16(a.v, *bp, acc[t], 0, 0, 0);
    }
  }
  int orow = row0 + w * 16 + quad * 4;
#pragma unroll
  for (int t = 0; t < 4; t++) {
    int col = col0 + t * 16 + mr;
    float bs = bias[col];
#pragma unroll
    for (int r = 0; r < 4; r++) {
      int rr = orow + r;
      if (rr < M) C[(size_t)rr * NN + col] = f2b(acc[t][r] + bs);
    }
  }
}

// ---- fused GATv2 attention + LDS ea dbuf + pk-FMA ea-dot + fused BN stats ----
template <int HC, int C, int WPN>
__global__ __launch_bounds__(256) void k_node_attn(
    const int* __restrict__ rowptr, const int2* __restrict__ epack,
    const u16* __restrict__ xl, const float* __restrict__ We, const float* __restrict__ att,
    const float* __restrict__ edge_attr, const float* __restrict__ ea_mean,
    const float* __restrict__ bo, u16* __restrict__ out,
    float* __restrict__ bnsum, float* __restrict__ bnsq) {
  __shared__ float sea[4][2][4][16];        // [wave][buf][edge][feat] = 2 KiB/block
  int lane = threadIdx.x & 63;
  int widx = threadIdx.x >> 6;
  int gwid = (blockIdx.x << 2) + widx;
  int nwaves = gridDim.x << 2;              // multiple of WPN by launch config
  int w = gwid % WPN;
  int i0 = gwid / WPN;
  int istride = nwaves / WPN;
  int c0 = w * 128 + lane * 2;
  f32x2 w2[FE];
#pragma unroll
  for (int k = 0; k < FE; k++) {
    float2 t = *reinterpret_cast<const float2*>(&We[k * HC + c0]);
    w2[k] = (f32x2){t.x, t.y};
  }
  float at0 = att[c0] * LOG2E, at1 = att[c0 + 1] * LOG2E;   // base-2 softmax
  f32x2 ews2 = {0.f, 0.f};
#pragma unroll
  for (int k = 0; k < FE; k++) ews2 += ea_mean[k] * w2[k];
  float b0 = bo[c0], b1 = bo[c0 + 1];
  constexpr int RED = C / 2;                // lanes per head
  constexpr int UN = 4;

  // lanes 0..15 each deposit one 16B chunk: edge = lane>>2, chunk = lane&3
  auto stage = [&](const int2* sep, int buf) {
    int y01 = (lane & 4) ? sep[1].y : sep[0].y;
    int y23 = (lane & 4) ? sep[3].y : sep[2].y;
    int eidv = (lane & 8) ? y23 : y01;
    int ec = (eidv < Ee) ? eidv : 0;
    const float* src = edge_attr + (size_t)ec * FE + (lane & 3) * 4;
    if (lane < 16) {
      __builtin_amdgcn_global_load_lds(
          (const __attribute__((address_space(1))) unsigned int*)src,
          (__attribute__((address_space(3))) unsigned int*)&sea[widx][buf][0][0],
          16, 0, 0);
    }
  };
  auto ea_dot_lds = [&](int eid, int buf, int jj) -> f32x2 {
    if (eid < Ee) {                          // wave-uniform branch
      const float4* ep = reinterpret_cast<const float4*>(&sea[widx][buf][jj][0]);
      f32x2 a = {0.f, 0.f};
#pragma unroll
      for (int k4 = 0; k4 < 4; k4++) {
        float4 u = ep[k4];
        f32x2 pA = {u.x, u.y};               // adjacent VGPRs -> ready-made pair
        f32x2 pB = {u.z, u.w};
        a = pk_fma_lo(pA, w2[4 * k4 + 0], a);
        a = pk_fma_hi(pA, w2[4 * k4 + 1], a);
        a = pk_fma_lo(pB, w2[4 * k4 + 2], a);
        a = pk_fma_hi(pB, w2[4 * k4 + 3], a);
      }
      return a;
    }
    return ews2;
  };

  if (i0 >= Nn) return;
  int p0 = rowptr[i0], p1 = rowptr[i0 + 1];
  ushort2 xdr = *reinterpret_cast<const ushort2*>(&xl[(size_t)i0 * HC + c0]);
  float bs0 = 0.f, bq0 = 0.f, bs1 = 0.f, bq1 = 0.f;   // fused BN stats

  for (int i = i0; i < Nn;) {
    // prefetch next node's rowptr + own row (hidden under this node's work)
    int inext = i + istride;
    int np0 = 0, np1 = 0;
    ushort2 nxdr = make_ushort2(0, 0);
    if (inext < Nn) {
      np0 = rowptr[inext];
      np1 = rowptr[inext + 1];
      nxdr = *reinterpret_cast<const ushort2*>(&xl[(size_t)inext * HC + c0]);
    }
    f32x2 xd = (f32x2){b2f(xdr.x), b2f(xdr.y)};
    int nb = (p1 - p0 + UN - 1) >> 2;       // >= 1 (self-loop)
    float m = -1e30f, l = 0.f;
    f32x2 acc = {0.f, 0.f};

    int2 se[UN];
#pragma unroll
    for (int j = 0; j < UN; j++) se[j] = epack[p0 + j];   // pad-safe, no clamp
    stage(se, 0);                           // batch 0 -> buf 0

    int pb = p0;
    for (int b = 0; b < nb; b++) {
      int buf = b & 1;
      asm volatile("s_waitcnt vmcnt(0)" ::: "memory");    // buf ready (prev stage drained)
      int sA[UN], eA[UN];
#pragma unroll
      for (int j = 0; j < UN; j++) {
        sA[j] = __builtin_amdgcn_readfirstlane(se[j].x);
        eA[j] = __builtin_amdgcn_readfirstlane(se[j].y);
      }
      ushort2 xr[UN];
#pragma unroll
      for (int j = 0; j < UN; j++)          // saddr-form coalesced gathers
        xr[j] = *reinterpret_cast<const ushort2*>(&xl[(size_t)sA[j] * HC + c0]);
      int pn = pb + UN;
      bool more = pn < p1;                  // wave-uniform
      if (more) {
#pragma unroll
        for (int j = 0; j < UN; j++) se[j] = epack[pn + j];   // pad-safe
      }
      // ---- current batch: ea from LDS (pk-FMA dot), logit, reduce ----
      f32x2 xs[UN];
      float part[UN];
#pragma unroll
      for (int j = 0; j < UN; j++) {
        f32x2 ew = ea_dot_lds(eA[j], buf, j);
        xs[j] = (f32x2){b2f(xr[j].x), b2f(xr[j].y)};
        f32x2 t = xs[j] + xd + ew;
        f32x2 tn = t * NS;
        float lk0 = fmaxf(t.x, tn.x), lk1 = fmaxf(t.y, tn.y);  // leaky_relu
        float pt = lk0 * at0 + lk1 * at1;               // log2-scaled
        pt = red_sum<RED>(pt);
        part[j] = (pb + j < p1) ? pt : -1e30f;
      }
      if (more) stage(se, buf ^ 1);         // mid-iter: stage batch b+1
      // ---- online softmax ----
      float mn = m;
#pragma unroll
      for (int j = 0; j < UN; j++) mn = fmaxf(mn, part[j]);
      float sc = __builtin_amdgcn_exp2f(m - mn);
      float a[UN], asum = 0.f;
      f32x2 ax = {0.f, 0.f};
#pragma unroll
      for (int j = 0; j < UN; j++) {
        a[j] = __builtin_amdgcn_exp2f(part[j] - mn);      // masked -> 0
        asum += a[j];
        ax += a[j] * xs[j];
      }
      l = l * sc + asum;
      acc = acc * sc + ax;
      m = mn;
      pb = pn;
    }
    float inv = 1.f / (l + 1e-16f);
    f32x2 v = {acc.x * inv + b0, acc.y * inv + b1};
    u16 r0 = f2b(v.x), r1 = f2b(v.y);
    ushort2 ru; ru.x = r0; ru.y = r1;
    *reinterpret_cast<ushort2*>(&out[(size_t)i * HC + c0]) = ru;
    float v0 = b2f(r0), v1 = b2f(r1);       // rounded values (bit-match old bn_stats)
    bs0 += v0; bq0 += v0 * v0; bs1 += v1; bq1 += v1 * v1;
    i = inext; p0 = np0; p1 = np1; xdr = nxdr;
  }
  atomicAdd(&bnsum[c0], bs0);     atomicAdd(&bnsq[c0], bq0);
  atomicAdd(&bnsum[c0 + 1], bs1); atomicAdd(&bnsq[c0 + 1], bq1);
}

// ------- layer 3 GEMV (with fused BN+ELU on h2) -------
__global__ __launch_bounds__(256) void k_gemv3(const u16* __restrict__ h2,
                                               const float2* __restrict__ coef,
                                               const float* __restrict__ W3l, const float* __restrict__ b3l,
                                               const float* __restrict__ W3r, const float* __restrict__ b3r,
                                               float* __restrict__ xl3, float* __restrict__ xr3) {
  int lane = threadIdx.x & 63;
  int i = (blockIdx.x << 2) + (threadIdx.x >> 6);
  if (i >= Nn) return;
  float2 ca = coef[lane], cb = coef[64 + lane];
  float a = b2f(h2[(long)i * HC2 + lane]) * ca.x + ca.y;
  a = a > 0.f ? a : __expf(a) - 1.f;
  float b = b2f(h2[(long)i * HC2 + 64 + lane]) * cb.x + cb.y;
  b = b > 0.f ? b : __expf(b) - 1.f;
  float pl = a * W3l[lane] + b * W3l[64 + lane];
  float pr = a * W3r[lane] + b * W3r[64 + lane];
  for (int o = 1; o < 64; o <<= 1) { pl += __shfl_xor(pl, o); pr += __shfl_xor(pr, o); }
  if (lane == 0) { xl3[i] = pl + b3l[0]; xr3[i] = pr + b3r[0]; }
}

// 16 nodes per block; 16 lanes per node
__global__ __launch_bounds__(256) void k_final3(
    const int* __restrict__ rowptr, const int2* __restrict__ epack,
    const float* __restrict__ xl3, const float* __restrict__ xr3,
    const float* __restrict__ We3, const float* __restrict__ att3,
    const float* __restrict__ edge_attr, const float* __restrict__ ea_mean,
    const float* __restrict__ bo3, float* __restrict__ out) {
  int t = threadIdx.x;
  int lane16 = t & 15;
  int i = blockIdx.x * 16 + (t >> 4);
  if (i >= Nn) return;
  float we[FE];
#pragma unroll
  for (int k4 = 0; k4 < 4; k4++) {
    float4 u = reinterpret_cast<const float4*>(We3)[k4];
    we[4 * k4] = u.x; we[4 * k4 + 1] = u.y; we[4 * k4 + 2] = u.z; we[4 * k4 + 3] = u.w;
  }
  float at = att3[0];
  float ews = 0.f;
#pragma unroll
  for (int k = 0; k < FE; k++) ews += ea_mean[k] * we[k];
  float xd = xr3[i];
  int p0 = rowptr[i], p1 = rowptr[i + 1];
  float m = -1e30f, l = 0.f, o = 0.f;
  for (int p = p0 + lane16; p < p1; p += 16) {
    int2 se = epack[p];
    int s = se.x, eid = se.y;
    float ew;
    if (eid < Ee) {
      const float4* ep = reinterpret_cast<const float4*>(&edge_attr[(size_t)eid * FE]);
      ew = 0.f;
#pragma unroll
      for (int k4 = 0; k4 < 4; k4++) {
        float4 u = ep[k4];
        ew += u.x * we[4 * k4] + u.y * we[4 * k4 + 1] + u.z * we[4 * k4 + 2] + u.w * we[4 * k4 + 3];
      }
    } else ew = ews;
    float xsv = xl3[s];
    float tt = xsv + xd + ew;
    float v = tt > 0.f ? tt : NS * tt;
    float logit = v * at;
    float mn = fmaxf(m, logit);
    float sc = __expf(m - mn);
    float a = __expf(logit - mn);
    l = l * sc + a;
    o = o * sc + a * xsv;
    m = mn;
  }
  float M = m;
#pragma unroll
  for (int off = 1; off < 16; off <<= 1) M = fmaxf(M, __shfl_xor(M, off));
  float adj = __expf(m - M);                       // lanes with no edges: 0
  float lw = l * adj, ow = o * adj;
#pragma unroll
  for (int off = 1; off < 16; off <<= 1) { lw += __shfl_xor(lw, off); ow += __shfl_xor(ow, off); }
  if (lane16 == 0) out[i] = ow / (lw + 1e-16f) + bo3[0];
}

extern "C" void kernel_launch(void* const* d_in, const int* in_sizes, int n_in,
                              void* d_out, int out_size, void* d_ws, size_t ws_size,
                              hipStream_t stream) {
  const float* x    = (const float*)d_in[0];
  const int*   ei   = (const int*)d_in[1];
  const float* ea   = (const float*)d_in[2];
  const float* W1   = (const float*)d_in[3];
  const float* b1   = (const float*)d_in[4];
  const float* We1  = (const float*)d_in[5];
  const float* att1 = (const float*)d_in[6];
  const float* bo1  = (const float*)d_in[7];
  const float* g1   = (const float*)d_in[8];
  const float* bt1  = (const float*)d_in[9];
  const float* W2   = (const float*)d_in[10];
  const float* b2   = (const float*)d_in[11];
  const float* We2  = (const float*)d_in[12];
  const float* att2 = (const float*)d_in[13];
  const float* bo2  = (const float*)d_in[14];
  const float* g2   = (const float*)d_in[15];
  const float* bt2  = (const float*)d_in[16];
  const float* W3l  = (const float*)d_in[17];
  const float* b3l  = (const float*)d_in[18];
  const float* W3r  = (const float*)d_in[19];
  const float* b3r  = (const float*)d_in[20];
  const float* We3  = (const float*)d_in[21];
  const float* att3 = (const float*)d_in[22];
  const float* bo3  = (const float*)d_in[23];
  float* out = (float*)d_out;

  char* ws = (char*)d_ws;
  size_t off = 0;
  auto alloc = [&](size_t bytes) -> void* {
    void* p = ws + off;
    off = (off + bytes + 255) & ~(size_t)255;
    return p;
  };
  int*    deg     = (int*)alloc((size_t)Nn * 4);
  int*    rowptr  = (int*)alloc((size_t)(Nn + 1) * 4);
  int*    cursor  = (int*)alloc((size_t)Nn * 4);
  int2*   epack   = (int2*)alloc((size_t)(ET + 4) * 8);   // +4 pad entries
  float*  ea_mean = (float*)alloc((size_t)FE * 4);
  float*  bn1s    = (float*)alloc(256 * 4);
  float*  bn1q    = (float*)alloc(256 * 4);
  float*  bn2s    = (float*)alloc(128 * 4);
  float*  bn2q    = (float*)alloc(128 * 4);
  float2* bncoef  = (float2*)alloc(256 * 8);
  float*  xl3     = (float*)alloc((size_t)Nn * 4);
  float*  xr3     = (float*)alloc((size_t)Nn * 4);
  u16*    xlA     = (u16*)alloc((size_t)Nn * 256 * 2);   // xl1 / xl2 (bf16 internal)
  u16*    hB      = (u16*)alloc((size_t)Nn * 256 * 2);   // h1 / h2 (bf16 internal, pre-BN)
  // total ≈ 57 MB (proven footprint)

  k_init<<<512, 256, 0, stream>>>(deg, cursor, ea_mean, bn1s, bn1q, bn2s, bn2q);
  k_deg_mean<<<(ET + 255) / 256, 256, 0, stream>>>(ei, ea, deg, ea_mean);
  k_scan<<<1, 1024, 0, stream>>>(deg, rowptr);
  k_scatter<<<(ET + 255) / 256, 256, 0, stream>>>(ei, rowptr, cursor, epack);

  // ---- layer 1 (BN stats fused into attn epilogue) ----
  k_gemm_mfma<FIN, HC1, float, false><<<dim3(HC1 / 64, (Nn + 63) / 64), 256, 0, stream>>>(
      x, W1, b1, xlA, nullptr, Nn);
  k_node_attn<HC1, C1, 2><<<2048, 256, 0, stream>>>(rowptr, epack, xlA, We1, att1,
                                                    ea, ea_mean, bo1, hB, bn1s, bn1q);
  k_bn_coef<<<1, 256, 0, stream>>>(bn1s, bn1q, g1, bt1, bncoef, HC1);

  // ---- layer 2 (BN1+ELU fused into A-load; BN2 stats fused into attn) ----
  k_gemm_mfma<HC1, HC2, u16, true><<<dim3(HC2 / 64, (Nn + 63) / 64), 256, 0, stream>>>(
      hB, W2, b2, xlA, bncoef, Nn);
  k_node_attn<HC2, C2, 1><<<2048, 256, 0, stream>>>(rowptr, epack, xlA, We2, att2,
                                                    ea, ea_mean, bo2, hB, bn2s, bn2q);
  k_bn_coef<<<1, 256, 0, stream>>>(bn2s, bn2q, g2, bt2, bncoef, HC2);

  // ---- layer 3 (BN2+ELU fused into h2 load) ----
  k_gemv3<<<(Nn + 3) / 4, 256, 0, stream>>>(hB, bncoef, W3l, b3l, W3r, b3r, xl3, xr3);
  k_final3<<<(Nn + 15) / 16, 256, 0, stream>>>(rowptr, epack, xl3, xr3, We3, att3,
                                               ea, ea_mean, bo3, out);
}

// Round 10
// 647.988 us; speedup vs baseline: 1.6446x; 1.6446x over previous
//
#include <hip/hip_runtime.h>

typedef unsigned short u16;   // raw bf16 bits (INTERNAL storage only)
typedef __attribute__((ext_vector_type(4))) float f32x4;
typedef __attribute__((ext_vector_type(2))) float f32x2;
typedef __attribute__((ext_vector_type(8))) short bf16x8;

constexpr int Nn  = 50000;
constexpr int Ee  = 500000;
constexpr int ET  = Nn + Ee;      // edges incl. self-loops
constexpr int FIN = 128;
constexpr int FE  = 16;
constexpr int Hh  = 8;
constexpr int C1  = 32, HC1 = 256;
constexpr int C2  = 16, HC2 = 128;
constexpr float NS  = 0.2f;
constexpr float EPS = 1e-5f;
constexpr float LOG2E = 1.44269504088896340736f;
constexpr int ATTN_BLOCKS = 2048;
constexpr int NWAVES = ATTN_BLOCKS * 4;    // 8192 waves in attn launch

__device__ __forceinline__ float b2f(u16 u) { return __uint_as_float(((unsigned)u) << 16); }
__device__ __forceinline__ u16 f2b(float f) {
  unsigned u = __float_as_uint(f);
  u += 0x7FFF + ((u >> 16) & 1);          // round-to-nearest-even
  return (u16)(u >> 16);
}

// ---- packed-f32 VOP3P helpers (encoding HW-verified by R6's passing run) ----
__device__ __forceinline__ f32x2 pk_fma_lo(f32x2 s, f32x2 w, f32x2 acc) {
  asm("v_pk_fma_f32 %0, %1, %2, %0 op_sel:[0,0,0] op_sel_hi:[0,1,1]"
      : "+v"(acc) : "v"(s), "v"(w));
  return acc;
}
__device__ __forceinline__ f32x2 pk_fma_hi(f32x2 s, f32x2 w, f32x2 acc) {
  asm("v_pk_fma_f32 %0, %1, %2, %0 op_sel:[1,0,0] op_sel_hi:[1,1,1]"
      : "+v"(acc) : "v"(s), "v"(w));
  return acc;
}

// DPP butterfly sum over RED lanes (RED = 8 or 16). VALU-only: no lgkmcnt.
template <int RED>
__device__ __forceinline__ float red_sum(float v) {
  v += __int_as_float(__builtin_amdgcn_update_dpp(0, __float_as_int(v), 0xB1, 0xF, 0xF, true));
  v += __int_as_float(__builtin_amdgcn_update_dpp(0, __float_as_int(v), 0x4E, 0xF, 0xF, true));
  v += __int_as_float(__builtin_amdgcn_update_dpp(0, __float_as_int(v), 0x141, 0xF, 0xF, true));
  if constexpr (RED == 16)
    v += __int_as_float(__builtin_amdgcn_update_dpp(0, __float_as_int(v), 0x140, 0xF, 0xF, true));
  return v;
}

// ---------------- init ----
__global__ void k_init(int* __restrict__ deg, int* __restrict__ cursor, float* __restrict__ ea_mean) {
  int t = blockIdx.x * 256 + threadIdx.x;
  int stride = gridDim.x * 256;
  for (int i = t; i < Nn; i += stride) { deg[i] = 0; cursor[i] = 0; }
  if (t < FE) ea_mean[t] = 0.f;
}

// ---------------- degree histogram + edge_attr mean ----
__global__ void k_deg_mean(const int* __restrict__ ei, const float* __restrict__ ea,
                           int* __restrict__ deg, float* __restrict__ ea_mean) {
  int t = threadIdx.x;
  int e = blockIdx.x * 256 + t;
  if (e < ET) {
    int d = (e < Ee) ? ei[Ee + e] : (e - Ee);
    if ((unsigned)d >= (unsigned)Nn) d = 0;   // safety clamp
    atomicAdd(&deg[d], 1);
  }
  __shared__ float s[256];
  int f  = t & 15;
  int r0 = (t >> 4) + blockIdx.x * 16;
  float acc = 0.f;
  for (int r = r0; r < Ee; r += gridDim.x * 16) acc += ea[r * FE + f];
  s[t] = acc;
  __syncthreads();
  if (t < 16) {
    float v = 0.f;
    for (int r = 0; r < 16; r++) v += s[r * 16 + t];
    atomicAdd(&ea_mean[t], v * (1.f / Ee));
  }
}

__global__ __launch_bounds__(1024) void k_scan(const int* __restrict__ deg, int* __restrict__ rowptr) {
  const int T = 1024;
  int t = threadIdx.x;
  const int CH = (Nn + T - 1) / T;  // 49
  int base = t * CH;
  int sum = 0;
  for (int i = 0; i < CH; i++) {
    int idx = base + i;
    if (idx < Nn) sum += deg[idx];
  }
  __shared__ int s[T];
  s[t] = sum;
  __syncthreads();
  for (int off = 1; off < T; off <<= 1) {
    int v = (t >= off) ? s[t - off] : 0;
    __syncthreads();
    s[t] += v;
    __syncthreads();
  }
  int run = (t == 0) ? 0 : s[t - 1];
  for (int i = 0; i < CH; i++) {
    int idx = base + i;
    if (idx < Nn) { rowptr[idx] = run; run += deg[idx]; }
  }
  if (t == T - 1) rowptr[Nn] = run;  // == ET
}

// scatter (dst-sorted); pads epack[ET..ET+3] so the attn kernel needs no clamps
__global__ void k_scatter(const int* __restrict__ ei, const int* __restrict__ rowptr,
                          int* __restrict__ cursor, int2* __restrict__ epack) {
  int e = blockIdx.x * 256 + threadIdx.x;
  if (e >= ET) return;
  if (e < 4) epack[ET + e] = make_int2(0, Ee);    // pad: s=0 (safe gather), eid=Ee (mean path)
  int s, d;
  if (e < Ee) { s = ei[e]; d = ei[Ee + e]; } else { s = d = e - Ee; }
  if ((unsigned)s >= (unsigned)Nn) s = 0;   // safety clamp
  if ((unsigned)d >= (unsigned)Nn) d = 0;
  int pos = rowptr[d] + atomicAdd(&cursor[d], 1);
  epack[pos] = make_int2(s, e);
}

// ---- BN partial reduction + coefficients: one block per channel pair ----
// bnpart[gwid*64+lane] = {sum_c0, sq_c0, sum_c1, sq_c1}, written by every attn wave.
// Replaces k_bn_stats + k_bn_coef: plain stores in attn, tree reduce here (no atomics).
template <int WPN>
__global__ __launch_bounds__(256) void k_bn_coef_red(
    const float4* __restrict__ bnpart, const float* __restrict__ g,
    const float* __restrict__ bt, float2* __restrict__ coef) {
  constexpr int NW = NWAVES / WPN;          // partials per channel pair
  int b = blockIdx.x;                       // 64*WPN blocks
  int w = b >> 6, lane = b & 63;
  int t = threadIdx.x;
  float4 s = make_float4(0.f, 0.f, 0.f, 0.f);
  for (int k = t; k < NW; k += 256) {
    float4 p = bnpart[(size_t)(k * WPN + w) * 64 + lane];
    s.x += p.x; s.y += p.y; s.z += p.z; s.w += p.w;
  }
  __shared__ float4 red[256];
  red[t] = s;
  __syncthreads();
  for (int off = 128; off > 0; off >>= 1) {
    if (t < off) {
      float4 o = red[t + off];
      red[t].x += o.x; red[t].y += o.y; red[t].z += o.z; red[t].w += o.w;
    }
    __syncthreads();
  }
  if (t == 0) {
    float4 tot = red[0];
    int c0 = w * 128 + lane * 2;
    float mu0 = tot.x * (1.f / Nn);
    float var0 = tot.y * (1.f / Nn) - mu0 * mu0;
    float sc0 = g[c0] * rsqrtf(var0 + EPS);
    coef[c0] = make_float2(sc0, bt[c0] - sc0 * mu0);
    float mu1 = tot.z * (1.f / Nn);
    float var1 = tot.w * (1.f / Nn) - mu1 * mu1;
    float sc1 = g[c0 + 1] * rsqrtf(var1 + EPS);
    coef[c0 + 1] = make_float2(sc1, bt[c0 + 1] - sc1 * mu1);
  }
}

// ------- MFMA bf16 GEMM -------
template <int KK, int NN, typename AT, bool FUSE>
__global__ __launch_bounds__(256) void k_gemm_mfma(const AT* __restrict__ A, const float* __restrict__ W,
                                                   const float* __restrict__ bias, u16* __restrict__ C,
                                                   const float2* __restrict__ coef, int M) {
  constexpr int WT = KK + 8;
  __shared__ u16 Wt[64 * WT];
  int tid = threadIdx.x;
  int col0 = blockIdx.x * 64;
  int row0 = blockIdx.y * 64;
  for (int idx = tid; idx < KK * 64; idx += 256) {   // stage W -> LDS (transposed, bf16)
    int k = idx >> 6, c = idx & 63;
    Wt[c * WT + k] = f2b(W[(size_t)k * NN + col0 + c]);
  }
  __syncthreads();
  int lane = tid & 63;
  int w = tid >> 6;
  int mr = lane & 15, quad = lane >> 4;
  int row = row0 + w * 16 + mr;
  f32x4 acc[4];
#pragma unroll
  for (int t = 0; t < 4; t++) acc[t] = (f32x4){0.f, 0.f, 0.f, 0.f};
  union Frag { bf16x8 v; u16 u[8]; };
  for (int kb = 0; kb < KK; kb += 32) {
    Frag a;
    if (row < M) {
      if constexpr (sizeof(AT) == 4) {               // fp32 input -> convert
        const float* ap = (const float*)&A[(size_t)row * KK + kb + quad * 8];
        float4 a0 = *reinterpret_cast<const float4*>(ap);
        float4 a1 = *reinterpret_cast<const float4*>(ap + 4);
        a.u[0] = f2b(a0.x); a.u[1] = f2b(a0.y); a.u[2] = f2b(a0.z); a.u[3] = f2b(a0.w);
        a.u[4] = f2b(a1.x); a.u[5] = f2b(a1.y); a.u[6] = f2b(a1.z); a.u[7] = f2b(a1.w);
      } else {                                       // bf16 internal
        a.v = *reinterpret_cast<const bf16x8*>(&A[(size_t)row * KK + kb + quad * 8]);
        if constexpr (FUSE) {
          int k0 = kb + quad * 8;
#pragma unroll
          for (int j = 0; j < 8; j++) {
            float2 c2 = coef[k0 + j];
            float y = b2f(a.u[j]) * c2.x + c2.y;
            y = y > 0.f ? y : __expf(y) - 1.f;       // ELU
            a.u[j] = f2b(y);
          }
        }
      }
    } else {
#pragma unroll
      for (int j = 0; j < 8; j++) a.u[j] = 0;
    }
#pragma unroll
    for (int t = 0; t < 4; t++) {
      const bf16x8* bp = reinterpret_cast<const bf16x8*>(&Wt[(t * 16 + mr) * WT + kb + quad * 8]);
      acc[t] = __builtin_amdgcn_mfma_f32_16x16x32_bf16(a.v, *bp, acc[t], 0, 0, 0);
    }
  }
  int orow = row0 + w * 16 + quad * 4;
#pragma unroll
  for (int t = 0; t < 4; t++) {
    int col = col0 + t * 16 + mr;
    float bs = bias[col];
#pragma unroll
    for (int r = 0; r < 4; r++) {
      int rr = orow + r;
      if (rr < M) C[(size_t)rr * NN + col] = f2b(acc[t][r] + bs);
    }
  }
}

// ---- fused GATv2 attention + LDS ea dbuf + pk-FMA ea-dot
//      + BN stats via per-wave PLAIN partial stores (no atomics) ----
template <int HC, int C, int WPN>
__global__ __launch_bounds__(256) void k_node_attn(
    const int* __restrict__ rowptr, const int2* __restrict__ epack,
    const u16* __restrict__ xl, const float* __restrict__ We, const float* __restrict__ att,
    const float* __restrict__ edge_attr, const float* __restrict__ ea_mean,
    const float* __restrict__ bo, u16* __restrict__ out,
    float4* __restrict__ bnpart) {
  __shared__ float sea[4][2][4][16];        // [wave][buf][edge][feat] = 2 KiB/block
  int lane = threadIdx.x & 63;
  int widx = threadIdx.x >> 6;
  int gwid = (blockIdx.x << 2) + widx;
  int nwaves = gridDim.x << 2;              // multiple of WPN by launch config
  int w = gwid % WPN;
  int i0 = gwid / WPN;
  int istride = nwaves / WPN;
  int c0 = w * 128 + lane * 2;
  f32x2 w2[FE];
#pragma unroll
  for (int k = 0; k < FE; k++) {
    float2 t = *reinterpret_cast<const float2*>(&We[k * HC + c0]);
    w2[k] = (f32x2){t.x, t.y};
  }
  float at0 = att[c0] * LOG2E, at1 = att[c0 + 1] * LOG2E;   // base-2 softmax
  f32x2 ews2 = {0.f, 0.f};
#pragma unroll
  for (int k = 0; k < FE; k++) ews2 += ea_mean[k] * w2[k];
  float b0 = bo[c0], b1 = bo[c0 + 1];
  constexpr int RED = C / 2;                // lanes per head
  constexpr int UN = 4;

  // lanes 0..15 each deposit one 16B chunk: edge = lane>>2, chunk = lane&3
  auto stage = [&](const int2* sep, int buf) {
    int y01 = (lane & 4) ? sep[1].y : sep[0].y;
    int y23 = (lane & 4) ? sep[3].y : sep[2].y;
    int eidv = (lane & 8) ? y23 : y01;
    int ec = (eidv < Ee) ? eidv : 0;
    const float* src = edge_attr + (size_t)ec * FE + (lane & 3) * 4;
    if (lane < 16) {
      __builtin_amdgcn_global_load_lds(
          (const __attribute__((address_space(1))) unsigned int*)src,
          (__attribute__((address_space(3))) unsigned int*)&sea[widx][buf][0][0],
          16, 0, 0);
    }
  };
  auto ea_dot_lds = [&](int eid, int buf, int jj) -> f32x2 {
    if (eid < Ee) {                          // wave-uniform branch
      const float4* ep = reinterpret_cast<const float4*>(&sea[widx][buf][jj][0]);
      f32x2 a = {0.f, 0.f};
#pragma unroll
      for (int k4 = 0; k4 < 4; k4++) {
        float4 u = ep[k4];
        f32x2 pA = {u.x, u.y};               // adjacent VGPRs -> ready-made pair
        f32x2 pB = {u.z, u.w};
        a = pk_fma_lo(pA, w2[4 * k4 + 0], a);
        a = pk_fma_hi(pA, w2[4 * k4 + 1], a);
        a = pk_fma_lo(pB, w2[4 * k4 + 2], a);
        a = pk_fma_hi(pB, w2[4 * k4 + 3], a);
      }
      return a;
    }
    return ews2;
  };

  float bs0 = 0.f, bq0 = 0.f, bs1 = 0.f, bq1 = 0.f;   // BN partials
  if (i0 >= Nn) {                           // never triggers at current config; defensive
    bnpart[(size_t)gwid * 64 + lane] = make_float4(0.f, 0.f, 0.f, 0.f);
    return;
  }
  int p0 = rowptr[i0], p1 = rowptr[i0 + 1];
  ushort2 xdr = *reinterpret_cast<const ushort2*>(&xl[(size_t)i0 * HC + c0]);

  for (int i = i0; i < Nn;) {
    // prefetch next node's rowptr + own row (hidden under this node's work)
    int inext = i + istride;
    int np0 = 0, np1 = 0;
    ushort2 nxdr = make_ushort2(0, 0);
    if (inext < Nn) {
      np0 = rowptr[inext];
      np1 = rowptr[inext + 1];
      nxdr = *reinterpret_cast<const ushort2*>(&xl[(size_t)inext * HC + c0]);
    }
    f32x2 xd = (f32x2){b2f(xdr.x), b2f(xdr.y)};
    int nb = (p1 - p0 + UN - 1) >> 2;       // >= 1 (self-loop)
    float m = -1e30f, l = 0.f;
    f32x2 acc = {0.f, 0.f};

    int2 se[UN];
#pragma unroll
    for (int j = 0; j < UN; j++) se[j] = epack[p0 + j];   // pad-safe, no clamp
    stage(se, 0);                           // batch 0 -> buf 0

    int pb = p0;
    for (int b = 0; b < nb; b++) {
      int buf = b & 1;
      asm volatile("s_waitcnt vmcnt(0)" ::: "memory");    // buf ready (prev stage drained)
      int sA[UN], eA[UN];
#pragma unroll
      for (int j = 0; j < UN; j++) {
        sA[j] = __builtin_amdgcn_readfirstlane(se[j].x);
        eA[j] = __builtin_amdgcn_readfirstlane(se[j].y);
      }
      ushort2 xr[UN];
#pragma unroll
      for (int j = 0; j < UN; j++)          // saddr-form coalesced gathers
        xr[j] = *reinterpret_cast<const ushort2*>(&xl[(size_t)sA[j] * HC + c0]);
      int pn = pb + UN;
      bool more = pn < p1;                  // wave-uniform
      if (more) {
#pragma unroll
        for (int j = 0; j < UN; j++) se[j] = epack[pn + j];   // pad-safe
      }
      // ---- current batch: ea from LDS (pk-FMA dot), logit, reduce ----
      f32x2 xs[UN];
      float part[UN];
#pragma unroll
      for (int j = 0; j < UN; j++) {
        f32x2 ew = ea_dot_lds(eA[j], buf, j);
        xs[j] = (f32x2){b2f(xr[j].x), b2f(xr[j].y)};
        f32x2 t = xs[j] + xd + ew;
        f32x2 tn = t * NS;
        float lk0 = fmaxf(t.x, tn.x), lk1 = fmaxf(t.y, tn.y);  // leaky_relu
        float pt = lk0 * at0 + lk1 * at1;               // log2-scaled
        pt = red_sum<RED>(pt);
        part[j] = (pb + j < p1) ? pt : -1e30f;
      }
      if (more) stage(se, buf ^ 1);         // mid-iter: stage batch b+1
      // ---- online softmax ----
      float mn = m;
#pragma unroll
      for (int j = 0; j < UN; j++) mn = fmaxf(mn, part[j]);
      float sc = __builtin_amdgcn_exp2f(m - mn);
      float a[UN], asum = 0.f;
      f32x2 ax = {0.f, 0.f};
#pragma unroll
      for (int j = 0; j < UN; j++) {
        a[j] = __builtin_amdgcn_exp2f(part[j] - mn);      // masked -> 0
        asum += a[j];
        ax += a[j] * xs[j];
      }
      l = l * sc + asum;
      acc = acc * sc + ax;
      m = mn;
      pb = pn;
    }
    float inv = 1.f / (l + 1e-16f);
    f32x2 v = {acc.x * inv + b0, acc.y * inv + b1};
    u16 r0 = f2b(v.x), r1 = f2b(v.y);
    ushort2 ru; ru.x = r0; ru.y = r1;
    *reinterpret_cast<ushort2*>(&out[(size_t)i * HC + c0]) = ru;
    float v0 = b2f(r0), v1 = b2f(r1);       // rounded values (match old bn_stats input)
    bs0 += v0; bq0 += v0 * v0; bs1 += v1; bq1 += v1 * v1;
    i = inext; p0 = np0; p1 = np1; xdr = nxdr;
  }
  // plain per-wave partial store -- NO atomics (the R6-R9 storm)
  bnpart[(size_t)gwid * 64 + lane] = make_float4(bs0, bq0, bs1, bq1);
}

// ------- layer 3 GEMV (with fused BN+ELU on h2) -------
__global__ __launch_bounds__(256) void k_gemv3(const u16* __restrict__ h2,
                                               const float2* __restrict__ coef,
                                               const float* __restrict__ W3l, const float* __restrict__ b3l,
                                               const float* __restrict__ W3r, const float* __restrict__ b3r,
                                               float* __restrict__ xl3, float* __restrict__ xr3) {
  int lane = threadIdx.x & 63;
  int i = (blockIdx.x << 2) + (threadIdx.x >> 6);
  if (i >= Nn) return;
  float2 ca = coef[lane], cb = coef[64 + lane];
  float a = b2f(h2[(long)i * HC2 + lane]) * ca.x + ca.y;
  a = a > 0.f ? a : __expf(a) - 1.f;
  float b = b2f(h2[(long)i * HC2 + 64 + lane]) * cb.x + cb.y;
  b = b > 0.f ? b : __expf(b) - 1.f;
  float pl = a * W3l[lane] + b * W3l[64 + lane];
  float pr = a * W3r[lane] + b * W3r[64 + lane];
  for (int o = 1; o < 64; o <<= 1) { pl += __shfl_xor(pl, o); pr += __shfl_xor(pr, o); }
  if (lane == 0) { xl3[i] = pl + b3l[0]; xr3[i] = pr + b3r[0]; }
}

// 16 nodes per block; 16 lanes per node
__global__ __launch_bounds__(256) void k_final3(
    const int* __restrict__ rowptr, const int2* __restrict__ epack,
    const float* __restrict__ xl3, const float* __restrict__ xr3,
    const float* __restrict__ We3, const float* __restrict__ att3,
    const float* __restrict__ edge_attr, const float* __restrict__ ea_mean,
    const float* __restrict__ bo3, float* __restrict__ out) {
  int t = threadIdx.x;
  int lane16 = t & 15;
  int i = blockIdx.x * 16 + (t >> 4);
  if (i >= Nn) return;
  float we[FE];
#pragma unroll
  for (int k4 = 0; k4 < 4; k4++) {
    float4 u = reinterpret_cast<const float4*>(We3)[k4];
    we[4 * k4] = u.x; we[4 * k4 + 1] = u.y; we[4 * k4 + 2] = u.z; we[4 * k4 + 3] = u.w;
  }
  float at = att3[0];
  float ews = 0.f;
#pragma unroll
  for (int k = 0; k < FE; k++) ews += ea_mean[k] * we[k];
  float xd = xr3[i];
  int p0 = rowptr[i], p1 = rowptr[i + 1];
  float m = -1e30f, l = 0.f, o = 0.f;
  for (int p = p0 + lane16; p < p1; p += 16) {
    int2 se = epack[p];
    int s = se.x, eid = se.y;
    float ew;
    if (eid < Ee) {
      const float4* ep = reinterpret_cast<const float4*>(&edge_attr[(size_t)eid * FE]);
      ew = 0.f;
#pragma unroll
      for (int k4 = 0; k4 < 4; k4++) {
        float4 u = ep[k4];
        ew += u.x * we[4 * k4] + u.y * we[4 * k4 + 1] + u.z * we[4 * k4 + 2] + u.w * we[4 * k4 + 3];
      }
    } else ew = ews;
    float xsv = xl3[s];
    float tt = xsv + xd + ew;
    float v = tt > 0.f ? tt : NS * tt;
    float logit = v * at;
    float mn = fmaxf(m, logit);
    float sc = __expf(m - mn);
    float a = __expf(logit - mn);
    l = l * sc + a;
    o = o * sc + a * xsv;
    m = mn;
  }
  float M = m;
#pragma unroll
  for (int off = 1; off < 16; off <<= 1) M = fmaxf(M, __shfl_xor(M, off));
  float adj = __expf(m - M);                       // lanes with no edges: 0
  float lw = l * adj, ow = o * adj;
#pragma unroll
  for (int off = 1; off < 16; off <<= 1) { lw += __shfl_xor(lw, off); ow += __shfl_xor(ow, off); }
  if (lane16 == 0) out[i] = ow / (lw + 1e-16f) + bo3[0];
}

extern "C" void kernel_launch(void* const* d_in, const int* in_sizes, int n_in,
                              void* d_out, int out_size, void* d_ws, size_t ws_size,
                              hipStream_t stream) {
  const float* x    = (const float*)d_in[0];
  const int*   ei   = (const int*)d_in[1];
  const float* ea   = (const float*)d_in[2];
  const float* W1   = (const float*)d_in[3];
  const float* b1   = (const float*)d_in[4];
  const float* We1  = (const float*)d_in[5];
  const float* att1 = (const float*)d_in[6];
  const float* bo1  = (const float*)d_in[7];
  const float* g1   = (const float*)d_in[8];
  const float* bt1  = (const float*)d_in[9];
  const float* W2   = (const float*)d_in[10];
  const float* b2   = (const float*)d_in[11];
  const float* We2  = (const float*)d_in[12];
  const float* att2 = (const float*)d_in[13];
  const float* bo2  = (const float*)d_in[14];
  const float* g2   = (const float*)d_in[15];
  const float* bt2  = (const float*)d_in[16];
  const float* W3l  = (const float*)d_in[17];
  const float* b3l  = (const float*)d_in[18];
  const float* W3r  = (const float*)d_in[19];
  const float* b3r  = (const float*)d_in[20];
  const float* We3  = (const float*)d_in[21];
  const float* att3 = (const float*)d_in[22];
  const float* bo3  = (const float*)d_in[23];
  float* out = (float*)d_out;

  char* ws = (char*)d_ws;
  size_t off = 0;
  auto alloc = [&](size_t bytes) -> void* {
    void* p = ws + off;
    off = (off + bytes + 255) & ~(size_t)255;
    return p;
  };
  int*    deg     = (int*)alloc((size_t)Nn * 4);
  int*    rowptr  = (int*)alloc((size_t)(Nn + 1) * 4);
  int*    cursor  = (int*)alloc((size_t)Nn * 4);
  int2*   epack   = (int2*)alloc((size_t)(ET + 4) * 8);   // +4 pad entries
  float*  ea_mean = (float*)alloc((size_t)FE * 4);
  float2* bncoef  = (float2*)alloc(256 * 8);
  float*  xl3     = (float*)alloc((size_t)Nn * 4);
  float*  xr3     = (float*)alloc((size_t)Nn * 4);
  u16*    xlA     = (u16*)alloc((size_t)Nn * 256 * 2);   // xl1 / xl2 (bf16 internal)
  u16*    hB      = (u16*)alloc((size_t)Nn * 256 * 2);   // h1 / h2 (bf16 internal, pre-BN)
  float4* bnpart  = (float4*)alloc((size_t)NWAVES * 64 * 16);  // 8 MB partials
  // total ≈ 65 MB (< 74.6 MB proven available by R4's f32-split run)

  k_init<<<512, 256, 0, stream>>>(deg, cursor, ea_mean);
  k_deg_mean<<<(ET + 255) / 256, 256, 0, stream>>>(ei, ea, deg, ea_mean);
  k_scan<<<1, 1024, 0, stream>>>(deg, rowptr);
  k_scatter<<<(ET + 255) / 256, 256, 0, stream>>>(ei, rowptr, cursor, epack);

  // ---- layer 1 (BN stats via per-wave partial stores, reduced in k_bn_coef_red) ----
  k_gemm_mfma<FIN, HC1, float, false><<<dim3(HC1 / 64, (Nn + 63) / 64), 256, 0, stream>>>(
      x, W1, b1, xlA, nullptr, Nn);
  k_node_attn<HC1, C1, 2><<<ATTN_BLOCKS, 256, 0, stream>>>(rowptr, epack, xlA, We1, att1,
                                                           ea, ea_mean, bo1, hB, bnpart);
  k_bn_coef_red<2><<<128, 256, 0, stream>>>(bnpart, g1, bt1, bncoef);

  // ---- layer 2 (BN1+ELU fused into A-load; BN2 stats via partial stores) ----
  k_gemm_mfma<HC1, HC2, u16, true><<<dim3(HC2 / 64, (Nn + 63) / 64), 256, 0, stream>>>(
      hB, W2, b2, xlA, bncoef, Nn);
  k_node_attn<HC2, C2, 1><<<ATTN_BLOCKS, 256, 0, stream>>>(rowptr, epack, xlA, We2, att2,
                                                           ea, ea_mean, bo2, hB, bnpart);
  k_bn_coef_red<1><<<64, 256, 0, stream>>>(bnpart, g2, bt2, bncoef);

  // ---- layer 3 (BN2+ELU fused into h2 load) ----
  k_gemv3<<<(Nn + 3) / 4, 256, 0, stream>>>(hB, bncoef, W3l, b3l, W3r, b3r, xl3, xr3);
  k_final3<<<(Nn + 15) / 16, 256, 0, stream>>>(rowptr, epack, xl3, xr3, We3, att3,
                                               ea, ea_mean, bo3, out);
}

// Round 11
// 645.974 us; speedup vs baseline: 1.6497x; 1.0031x over previous
//
#include <hip/hip_runtime.h>

typedef unsigned short u16;   // raw bf16 bits (INTERNAL storage only)
typedef __attribute__((ext_vector_type(4))) float f32x4;
typedef __attribute__((ext_vector_type(2))) float f32x2;
typedef __attribute__((ext_vector_type(8))) short bf16x8;

constexpr int Nn  = 50000;
constexpr int Ee  = 500000;
constexpr int ET  = Nn + Ee;      // edges incl. self-loops
constexpr int FIN = 128;
constexpr int FE  = 16;
constexpr int Hh  = 8;
constexpr int C1  = 32, HC1 = 256;
constexpr int C2  = 16, HC2 = 128;
constexpr float NS  = 0.2f;
constexpr float EPS = 1e-5f;
constexpr float LOG2E = 1.44269504088896340736f;
constexpr int ATTN_BLOCKS = 2048;
constexpr int NWAVES = ATTN_BLOCKS * 4;    // 8192 waves in attn launch

__device__ __forceinline__ float b2f(u16 u) { return __uint_as_float(((unsigned)u) << 16); }
__device__ __forceinline__ u16 f2b(float f) {
  unsigned u = __float_as_uint(f);
  u += 0x7FFF + ((u >> 16) & 1);          // round-to-nearest-even
  return (u16)(u >> 16);
}

// DPP butterfly sum over RED lanes (RED = 8 or 16). VALU-only: no lgkmcnt.
template <int RED>
__device__ __forceinline__ float red_sum(float v) {
  v += __int_as_float(__builtin_amdgcn_update_dpp(0, __float_as_int(v), 0xB1, 0xF, 0xF, true));
  v += __int_as_float(__builtin_amdgcn_update_dpp(0, __float_as_int(v), 0x4E, 0xF, 0xF, true));
  v += __int_as_float(__builtin_amdgcn_update_dpp(0, __float_as_int(v), 0x141, 0xF, 0xF, true));
  if constexpr (RED == 16)
    v += __int_as_float(__builtin_amdgcn_update_dpp(0, __float_as_int(v), 0x140, 0xF, 0xF, true));
  return v;
}

// ---------------- init ----
__global__ void k_init(int* __restrict__ deg, int* __restrict__ cursor, float* __restrict__ ea_mean) {
  int t = blockIdx.x * 256 + threadIdx.x;
  int stride = gridDim.x * 256;
  for (int i = t; i < Nn; i += stride) { deg[i] = 0; cursor[i] = 0; }
  if (t < FE) ea_mean[t] = 0.f;
}

// ---------------- degree histogram + edge_attr mean ----
__global__ void k_deg_mean(const int* __restrict__ ei, const float* __restrict__ ea,
                           int* __restrict__ deg, float* __restrict__ ea_mean) {
  int t = threadIdx.x;
  int e = blockIdx.x * 256 + t;
  if (e < ET) {
    int d = (e < Ee) ? ei[Ee + e] : (e - Ee);
    if ((unsigned)d >= (unsigned)Nn) d = 0;   // safety clamp
    atomicAdd(&deg[d], 1);
  }
  __shared__ float s[256];
  int f  = t & 15;
  int r0 = (t >> 4) + blockIdx.x * 16;
  float acc = 0.f;
  for (int r = r0; r < Ee; r += gridDim.x * 16) acc += ea[r * FE + f];
  s[t] = acc;
  __syncthreads();
  if (t < 16) {
    float v = 0.f;
    for (int r = 0; r < 16; r++) v += s[r * 16 + t];
    atomicAdd(&ea_mean[t], v * (1.f / Ee));
  }
}

__global__ __launch_bounds__(1024) void k_scan(const int* __restrict__ deg, int* __restrict__ rowptr) {
  const int T = 1024;
  int t = threadIdx.x;
  const int CH = (Nn + T - 1) / T;  // 49
  int base = t * CH;
  int sum = 0;
  for (int i = 0; i < CH; i++) {
    int idx = base + i;
    if (idx < Nn) sum += deg[idx];
  }
  __shared__ int s[T];
  s[t] = sum;
  __syncthreads();
  for (int off = 1; off < T; off <<= 1) {
    int v = (t >= off) ? s[t - off] : 0;
    __syncthreads();
    s[t] += v;
    __syncthreads();
  }
  int run = (t == 0) ? 0 : s[t - 1];
  for (int i = 0; i < CH; i++) {
    int idx = base + i;
    if (idx < Nn) { rowptr[idx] = run; run += deg[idx]; }
  }
  if (t == T - 1) rowptr[Nn] = run;  // == ET
}

// scatter (dst-sorted); pads epack[ET..ET+3] so the attn kernel needs no clamps
__global__ void k_scatter(const int* __restrict__ ei, const int* __restrict__ rowptr,
                          int* __restrict__ cursor, int2* __restrict__ epack) {
  int e = blockIdx.x * 256 + threadIdx.x;
  if (e >= ET) return;
  if (e < 4) epack[ET + e] = make_int2(0, Ee);    // pad: s=0 (safe gather), eid=Ee (mean path)
  int s, d;
  if (e < Ee) { s = ei[e]; d = ei[Ee + e]; } else { s = d = e - Ee; }
  if ((unsigned)s >= (unsigned)Nn) s = 0;   // safety clamp
  if ((unsigned)d >= (unsigned)Nn) d = 0;
  int pos = rowptr[d] + atomicAdd(&cursor[d], 1);
  epack[pos] = make_int2(s, e);
}

// ---- BN partial reduction + coefficients: one block per channel pair ----
template <int WPN>
__global__ __launch_bounds__(256) void k_bn_coef_red(
    const float4* __restrict__ bnpart, const float* __restrict__ g,
    const float* __restrict__ bt, float2* __restrict__ coef) {
  constexpr int NW = NWAVES / WPN;          // partials per channel pair
  int b = blockIdx.x;                       // 64*WPN blocks
  int w = b >> 6, lane = b & 63;
  int t = threadIdx.x;
  float4 s = make_float4(0.f, 0.f, 0.f, 0.f);
  for (int k = t; k < NW; k += 256) {
    float4 p = bnpart[(size_t)(k * WPN + w) * 64 + lane];
    s.x += p.x; s.y += p.y; s.z += p.z; s.w += p.w;
  }
  __shared__ float4 red[256];
  red[t] = s;
  __syncthreads();
  for (int off = 128; off > 0; off >>= 1) {
    if (t < off) {
      float4 o = red[t + off];
      red[t].x += o.x; red[t].y += o.y; red[t].z += o.z; red[t].w += o.w;
    }
    __syncthreads();
  }
  if (t == 0) {
    float4 tot = red[0];
    int c0 = w * 128 + lane * 2;
    float mu0 = tot.x * (1.f / Nn);
    float var0 = tot.y * (1.f / Nn) - mu0 * mu0;
    float sc0 = g[c0] * rsqrtf(var0 + EPS);
    coef[c0] = make_float2(sc0, bt[c0] - sc0 * mu0);
    float mu1 = tot.z * (1.f / Nn);
    float var1 = tot.w * (1.f / Nn) - mu1 * mu1;
    float sc1 = g[c0 + 1] * rsqrtf(var1 + EPS);
    coef[c0 + 1] = make_float2(sc1, bt[c0 + 1] - sc1 * mu1);
  }
}

// ------- MFMA bf16 GEMM (1D grid, XCD-chunked block remap for A L2-reuse) -------
// Consecutive blockIdx round-robin across the 8 XCDs (private L2s), so the NN/64
// col-blocks of one row-block land on different XCDs and each re-fetches A from HBM.
// Bijective chunked remap (guide m157/m204) gives each XCD a contiguous (row,col)
// chunk: its A-slice fits the 4 MiB L2 and is fetched once.
template <int KK, int NN, typename AT, bool FUSE>
__global__ __launch_bounds__(256) void k_gemm_mfma(const AT* __restrict__ A, const float* __restrict__ W,
                                                   const float* __restrict__ bias, u16* __restrict__ C,
                                                   const float2* __restrict__ coef, int M) {
  int nblk = gridDim.x;
  int n = blockIdx.x;
  int q = nblk >> 3, r = nblk & 7;
  int xcd = n & 7, idx = n >> 3;
  int np = (xcd < r ? xcd * (q + 1) : r * (q + 1) + (xcd - r) * q) + idx;
  constexpr int XB = NN / 64;
  int col0 = (np % XB) * 64;
  int row0 = (np / XB) * 64;

  constexpr int WT = KK + 8;
  __shared__ u16 Wt[64 * WT];
  int tid = threadIdx.x;
  for (int idx2 = tid; idx2 < KK * 64; idx2 += 256) {   // stage W -> LDS (transposed, bf16)
    int k = idx2 >> 6, c = idx2 & 63;
    Wt[c * WT + k] = f2b(W[(size_t)k * NN + col0 + c]);
  }
  __syncthreads();
  int lane = tid & 63;
  int w = tid >> 6;
  int mr = lane & 15, quad = lane >> 4;
  int row = row0 + w * 16 + mr;
  f32x4 acc[4];
#pragma unroll
  for (int t = 0; t < 4; t++) acc[t] = (f32x4){0.f, 0.f, 0.f, 0.f};
  union Frag { bf16x8 v; u16 u[8]; };
  for (int kb = 0; kb < KK; kb += 32) {
    Frag a;
    if (row < M) {
      if constexpr (sizeof(AT) == 4) {               // fp32 input -> convert
        const float* ap = (const float*)&A[(size_t)row * KK + kb + quad * 8];
        float4 a0 = *reinterpret_cast<const float4*>(ap);
        float4 a1 = *reinterpret_cast<const float4*>(ap + 4);
        a.u[0] = f2b(a0.x); a.u[1] = f2b(a0.y); a.u[2] = f2b(a0.z); a.u[3] = f2b(a0.w);
        a.u[4] = f2b(a1.x); a.u[5] = f2b(a1.y); a.u[6] = f2b(a1.z); a.u[7] = f2b(a1.w);
      } else {                                       // bf16 internal
        a.v = *reinterpret_cast<const bf16x8*>(&A[(size_t)row * KK + kb + quad * 8]);
        if constexpr (FUSE) {
          int k0 = kb + quad * 8;
#pragma unroll
          for (int j = 0; j < 8; j++) {
            float2 c2 = coef[k0 + j];
            float y = b2f(a.u[j]) * c2.x + c2.y;
            y = y > 0.f ? y : __expf(y) - 1.f;       // ELU
            a.u[j] = f2b(y);
          }
        }
      }
    } else {
#pragma unroll
      for (int j = 0; j < 8; j++) a.u[j] = 0;
    }
#pragma unroll
    for (int t = 0; t < 4; t++) {
      const bf16x8* bp = reinterpret_cast<const bf16x8*>(&Wt[(t * 16 + mr) * WT + kb + quad * 8]);
      acc[t] = __builtin_amdgcn_mfma_f32_16x16x32_bf16(a.v, *bp, acc[t], 0, 0, 0);
    }
  }
  int orow = row0 + w * 16 + quad * 4;
#pragma unroll
  for (int t = 0; t < 4; t++) {
    int col = col0 + t * 16 + mr;
    float bs = bias[col];
#pragma unroll
    for (int r2 = 0; r2 < 4; r2++) {
      int rr = orow + r2;
      if (rr < M) C[(size_t)rr * NN + col] = f2b(acc[t][r2] + bs);
    }
  }
}

// ---- fused GATv2 attention + LDS ea dbuf + scalar (uniform) epack addressing
//      + BN stats via per-wave PLAIN partial stores (no atomics) ----
template <int HC, int C, int WPN>
__global__ __launch_bounds__(256) void k_node_attn(
    const int* __restrict__ rowptr, const int2* __restrict__ epack,
    const u16* __restrict__ xl, const float* __restrict__ We, const float* __restrict__ att,
    const float* __restrict__ edge_attr, const float* __restrict__ ea_mean,
    const float* __restrict__ bo, u16* __restrict__ out,
    float4* __restrict__ bnpart) {
  __shared__ float sea[4][2][4][16];        // [wave][buf][edge][feat] = 2 KiB/block
  int lane = threadIdx.x & 63;
  int widx = threadIdx.x >> 6;
  int gwid = (blockIdx.x << 2) + widx;
  int nwaves = gridDim.x << 2;              // multiple of WPN by launch config
  int w = gwid % WPN;
  int i0 = gwid / WPN;
  int istride = nwaves / WPN;
  int c0 = w * 128 + lane * 2;
  f32x2 w2[FE];
#pragma unroll
  for (int k = 0; k < FE; k++) {
    float2 t = *reinterpret_cast<const float2*>(&We[k * HC + c0]);
    w2[k] = (f32x2){t.x, t.y};
  }
  float at0 = att[c0] * LOG2E, at1 = att[c0 + 1] * LOG2E;   // base-2 softmax
  f32x2 ews2 = {0.f, 0.f};
#pragma unroll
  for (int k = 0; k < FE; k++) ews2 += ea_mean[k] * w2[k];
  float b0 = bo[c0], b1 = bo[c0 + 1];
  constexpr int RED = C / 2;                // lanes per head
  constexpr int UN = 4;

  // lanes 0..15 each deposit one 16B chunk: edge = lane>>2, chunk = lane&3
  auto stage = [&](const int2* sep, int buf) {
    int y01 = (lane & 4) ? sep[1].y : sep[0].y;
    int y23 = (lane & 4) ? sep[3].y : sep[2].y;
    int eidv = (lane & 8) ? y23 : y01;
    int ec = (eidv < Ee) ? eidv : 0;
    const float* src = edge_attr + (size_t)ec * FE + (lane & 3) * 4;
    if (lane < 16) {
      __builtin_amdgcn_global_load_lds(
          (const __attribute__((address_space(1))) unsigned int*)src,
          (__attribute__((address_space(3))) unsigned int*)&sea[widx][buf][0][0],
          16, 0, 0);
    }
  };
  auto ea_dot_lds = [&](int eid, int buf, int jj) -> f32x2 {
    if (eid < Ee) {                          // wave-uniform branch
      const float4* ep = reinterpret_cast<const float4*>(&sea[widx][buf][jj][0]);
      f32x2 a = {0.f, 0.f};
#pragma unroll
      for (int k4 = 0; k4 < 4; k4++) {
        float4 u = ep[k4];
        a += u.x * w2[4 * k4 + 0];
        a += u.y * w2[4 * k4 + 1];
        a += u.z * w2[4 * k4 + 2];
        a += u.w * w2[4 * k4 + 3];
      }
      return a;
    }
    return ews2;
  };

  float bs0 = 0.f, bq0 = 0.f, bs1 = 0.f, bq1 = 0.f;   // BN partials
  if (i0 >= Nn) {                           // never triggers at current config; defensive
    bnpart[(size_t)gwid * 64 + lane] = make_float4(0.f, 0.f, 0.f, 0.f);
    return;
  }
  // rowptr values forced to SGPR: the whole epack index chain becomes provably
  // wave-uniform -> compiler can use scalar (SMEM) loads for epack batches.
  int p0 = __builtin_amdgcn_readfirstlane(rowptr[i0]);
  int p1 = __builtin_amdgcn_readfirstlane(rowptr[i0 + 1]);
  ushort2 xdr = *reinterpret_cast<const ushort2*>(&xl[(size_t)i0 * HC + c0]);

  for (int i = i0; i < Nn;) {
    // prefetch next node's rowptr + own row (hidden under this node's work)
    int inext = i + istride;
    int np0 = 0, np1 = 0;
    ushort2 nxdr = make_ushort2(0, 0);
    if (inext < Nn) {
      np0 = __builtin_amdgcn_readfirstlane(rowptr[inext]);
      np1 = __builtin_amdgcn_readfirstlane(rowptr[inext + 1]);
      nxdr = *reinterpret_cast<const ushort2*>(&xl[(size_t)inext * HC + c0]);
    }
    f32x2 xd = (f32x2){b2f(xdr.x), b2f(xdr.y)};
    int nb = (p1 - p0 + UN - 1) >> 2;       // >= 1 (self-loop)
    float m = -1e30f, l = 0.f;
    f32x2 acc = {0.f, 0.f};

    int2 se[UN];
#pragma unroll
    for (int j = 0; j < UN; j++) se[j] = epack[p0 + j];   // uniform addr, pad-safe
    stage(se, 0);                           // batch 0 -> buf 0

    int pb = p0;
    for (int b = 0; b < nb; b++) {
      int buf = b & 1;
      asm volatile("s_waitcnt vmcnt(0)" ::: "memory");    // buf ready (prev stage drained)
      int sA[UN], eA[UN];
#pragma unroll
      for (int j = 0; j < UN; j++) {        // folds to no-op if se already scalar
        sA[j] = __builtin_amdgcn_readfirstlane(se[j].x);
        eA[j] = __builtin_amdgcn_readfirstlane(se[j].y);
      }
      ushort2 xr[UN];
#pragma unroll
      for (int j = 0; j < UN; j++)          // saddr-form coalesced gathers
        xr[j] = *reinterpret_cast<const ushort2*>(&xl[(size_t)sA[j] * HC + c0]);
      int pn = pb + UN;
      bool more = pn < p1;                  // wave-uniform
      if (more) {
#pragma unroll
        for (int j = 0; j < UN; j++) se[j] = epack[pn + j];   // uniform addr, pad-safe
      }
      // ---- current batch: ea from LDS, logit, reduce (C-scheduled) ----
      f32x2 xs[UN];
      float part[UN];
#pragma unroll
      for (int j = 0; j < UN; j++) {
        f32x2 ew = ea_dot_lds(eA[j], buf, j);
        xs[j] = (f32x2){b2f(xr[j].x), b2f(xr[j].y)};
        f32x2 t = xs[j] + xd + ew;
        f32x2 tn = t * NS;
        float lk0 = fmaxf(t.x, tn.x), lk1 = fmaxf(t.y, tn.y);  // leaky_relu
        float pt = lk0 * at0 + lk1 * at1;               // log2-scaled
        pt = red_sum<RED>(pt);
        part[j] = (pb + j < p1) ? pt : -1e30f;
      }
      if (more) stage(se, buf ^ 1);         // mid-iter: stage batch b+1
      // ---- online softmax ----
      float mn = m;
#pragma unroll
      for (int j = 0; j < UN; j++) mn = fmaxf(mn, part[j]);
      float sc = __builtin_amdgcn_exp2f(m - mn);
      float a[UN], asum = 0.f;
      f32x2 ax = {0.f, 0.f};
#pragma unroll
      for (int j = 0; j < UN; j++) {
        a[j] = __builtin_amdgcn_exp2f(part[j] - mn);      // masked -> 0
        asum += a[j];
        ax += a[j] * xs[j];
      }
      l = l * sc + asum;
      acc = acc * sc + ax;
      m = mn;
      pb = pn;
    }
    float inv = 1.f / (l + 1e-16f);
    f32x2 v = {acc.x * inv + b0, acc.y * inv + b1};
    u16 r0 = f2b(v.x), r1 = f2b(v.y);
    ushort2 ru; ru.x = r0; ru.y = r1;
    *reinterpret_cast<ushort2*>(&out[(size_t)i * HC + c0]) = ru;
    float v0 = b2f(r0), v1 = b2f(r1);       // rounded values (match old bn_stats input)
    bs0 += v0; bq0 += v0 * v0; bs1 += v1; bq1 += v1 * v1;
    i = inext; p0 = np0; p1 = np1; xdr = nxdr;
  }
  // plain per-wave partial store -- NO atomics (the R6-R9 storm)
  bnpart[(size_t)gwid * 64 + lane] = make_float4(bs0, bq0, bs1, bq1);
}

// ------- layer 3 GEMV (with fused BN+ELU on h2) -------
__global__ __launch_bounds__(256) void k_gemv3(const u16* __restrict__ h2,
                                               const float2* __restrict__ coef,
                                               const float* __restrict__ W3l, const float* __restrict__ b3l,
                                               const float* __restrict__ W3r, const float* __restrict__ b3r,
                                               float* __restrict__ xl3, float* __restrict__ xr3) {
  int lane = threadIdx.x & 63;
  int i = (blockIdx.x << 2) + (threadIdx.x >> 6);
  if (i >= Nn) return;
  float2 ca = coef[lane], cb = coef[64 + lane];
  float a = b2f(h2[(long)i * HC2 + lane]) * ca.x + ca.y;
  a = a > 0.f ? a : __expf(a) - 1.f;
  float b = b2f(h2[(long)i * HC2 + 64 + lane]) * cb.x + cb.y;
  b = b > 0.f ? b : __expf(b) - 1.f;
  float pl = a * W3l[lane] + b * W3l[64 + lane];
  float pr = a * W3r[lane] + b * W3r[64 + lane];
  for (int o = 1; o < 64; o <<= 1) { pl += __shfl_xor(pl, o); pr += __shfl_xor(pr, o); }
  if (lane == 0) { xl3[i] = pl + b3l[0]; xr3[i] = pr + b3r[0]; }
}

// 16 nodes per block; 16 lanes per node
__global__ __launch_bounds__(256) void k_final3(
    const int* __restrict__ rowptr, const int2* __restrict__ epack,
    const float* __restrict__ xl3, const float* __restrict__ xr3,
    const float* __restrict__ We3, const float* __restrict__ att3,
    const float* __restrict__ edge_attr, const float* __restrict__ ea_mean,
    const float* __restrict__ bo3, float* __restrict__ out) {
  int t = threadIdx.x;
  int lane16 = t & 15;
  int i = blockIdx.x * 16 + (t >> 4);
  if (i >= Nn) return;
  float we[FE];
#pragma unroll
  for (int k4 = 0; k4 < 4; k4++) {
    float4 u = reinterpret_cast<const float4*>(We3)[k4];
    we[4 * k4] = u.x; we[4 * k4 + 1] = u.y; we[4 * k4 + 2] = u.z; we[4 * k4 + 3] = u.w;
  }
  float at = att3[0];
  float ews = 0.f;
#pragma unroll
  for (int k = 0; k < FE; k++) ews += ea_mean[k] * we[k];
  float xd = xr3[i];
  int p0 = rowptr[i], p1 = rowptr[i + 1];
  float m = -1e30f, l = 0.f, o = 0.f;
  for (int p = p0 + lane16; p < p1; p += 16) {
    int2 se = epack[p];
    int s = se.x, eid = se.y;
    float ew;
    if (eid < Ee) {
      const float4* ep = reinterpret_cast<const float4*>(&edge_attr[(size_t)eid * FE]);
      ew = 0.f;
#pragma unroll
      for (int k4 = 0; k4 < 4; k4++) {
        float4 u = ep[k4];
        ew += u.x * we[4 * k4] + u.y * we[4 * k4 + 1] + u.z * we[4 * k4 + 2] + u.w * we[4 * k4 + 3];
      }
    } else ew = ews;
    float xsv = xl3[s];
    float tt = xsv + xd + ew;
    float v = tt > 0.f ? tt : NS * tt;
    float logit = v * at;
    float mn = fmaxf(m, logit);
    float sc = __expf(m - mn);
    float a = __expf(logit - mn);
    l = l * sc + a;
    o = o * sc + a * xsv;
    m = mn;
  }
  float M = m;
#pragma unroll
  for (int off = 1; off < 16; off <<= 1) M = fmaxf(M, __shfl_xor(M, off));
  float adj = __expf(m - M);                       // lanes with no edges: 0
  float lw = l * adj, ow = o * adj;
#pragma unroll
  for (int off = 1; off < 16; off <<= 1) { lw += __shfl_xor(lw, off); ow += __shfl_xor(ow, off); }
  if (lane16 == 0) out[i] = ow / (lw + 1e-16f) + bo3[0];
}

extern "C" void kernel_launch(void* const* d_in, const int* in_sizes, int n_in,
                              void* d_out, int out_size, void* d_ws, size_t ws_size,
                              hipStream_t stream) {
  const float* x    = (const float*)d_in[0];
  const int*   ei   = (const int*)d_in[1];
  const float* ea   = (const float*)d_in[2];
  const float* W1   = (const float*)d_in[3];
  const float* b1   = (const float*)d_in[4];
  const float* We1  = (const float*)d_in[5];
  const float* att1 = (const float*)d_in[6];
  const float* bo1  = (const float*)d_in[7];
  const float* g1   = (const float*)d_in[8];
  const float* bt1  = (const float*)d_in[9];
  const float* W2   = (const float*)d_in[10];
  const float* b2   = (const float*)d_in[11];
  const float* We2  = (const float*)d_in[12];
  const float* att2 = (const float*)d_in[13];
  const float* bo2  = (const float*)d_in[14];
  const float* g2   = (const float*)d_in[15];
  const float* bt2  = (const float*)d_in[16];
  const float* W3l  = (const float*)d_in[17];
  const float* b3l  = (const float*)d_in[18];
  const float* W3r  = (const float*)d_in[19];
  const float* b3r  = (const float*)d_in[20];
  const float* We3  = (const float*)d_in[21];
  const float* att3 = (const float*)d_in[22];
  const float* bo3  = (const float*)d_in[23];
  float* out = (float*)d_out;

  char* ws = (char*)d_ws;
  size_t off = 0;
  auto alloc = [&](size_t bytes) -> void* {
    void* p = ws + off;
    off = (off + bytes + 255) & ~(size_t)255;
    return p;
  };
  int*    deg     = (int*)alloc((size_t)Nn * 4);
  int*    rowptr  = (int*)alloc((size_t)(Nn + 1) * 4);
  int*    cursor  = (int*)alloc((size_t)Nn * 4);
  int2*   epack   = (int2*)alloc((size_t)(ET + 4) * 8);   // +4 pad entries
  float*  ea_mean = (float*)alloc((size_t)FE * 4);
  float2* bncoef  = (float2*)alloc(256 * 8);
  float*  xl3     = (float*)alloc((size_t)Nn * 4);
  float*  xr3     = (float*)alloc((size_t)Nn * 4);
  u16*    xlA     = (u16*)alloc((size_t)Nn * 256 * 2);   // xl1 / xl2 (bf16 internal)
  u16*    hB      = (u16*)alloc((size_t)Nn * 256 * 2);   // h1 / h2 (bf16 internal, pre-BN)
  float4* bnpart  = (float4*)alloc((size_t)NWAVES * 64 * 16);  // 8 MB partials
  // total ≈ 65 MB (< 74.6 MB proven available by R4's f32-split run)

  k_init<<<512, 256, 0, stream>>>(deg, cursor, ea_mean);
  k_deg_mean<<<(ET + 255) / 256, 256, 0, stream>>>(ei, ea, deg, ea_mean);
  k_scan<<<1, 1024, 0, stream>>>(deg, rowptr);
  k_scatter<<<(ET + 255) / 256, 256, 0, stream>>>(ei, rowptr, cursor, epack);

  const int RB = (Nn + 63) / 64;            // 782 row-blocks

  // ---- layer 1 (BN stats via per-wave partial stores, reduced in k_bn_coef_red) ----
  k_gemm_mfma<FIN, HC1, float, false><<<(HC1 / 64) * RB, 256, 0, stream>>>(
      x, W1, b1, xlA, nullptr, Nn);
  k_node_attn<HC1, C1, 2><<<ATTN_BLOCKS, 256, 0, stream>>>(rowptr, epack, xlA, We1, att1,
                                                           ea, ea_mean, bo1, hB, bnpart);
  k_bn_coef_red<2><<<128, 256, 0, stream>>>(bnpart, g1, bt1, bncoef);

  // ---- layer 2 (BN1+ELU fused into A-load; BN2 stats via partial stores) ----
  k_gemm_mfma<HC1, HC2, u16, true><<<(HC2 / 64) * RB, 256, 0, stream>>>(
      hB, W2, b2, xlA, bncoef, Nn);
  k_node_attn<HC2, C2, 1><<<ATTN_BLOCKS, 256, 0, stream>>>(rowptr, epack, xlA, We2, att2,
                                                           ea, ea_mean, bo2, hB, bnpart);
  k_bn_coef_red<1><<<64, 256, 0, stream>>>(bnpart, g2, bt2, bncoef);

  // ---- layer 3 (BN2+ELU fused into h2 load) ----
  k_gemv3<<<(Nn + 3) / 4, 256, 0, stream>>>(hB, bncoef, W3l, b3l, W3r, b3r, xl3, xr3);
  k_final3<<<(Nn + 15) / 16, 256, 0, stream>>>(rowptr, epack, xl3, xr3, We3, att3,
                                               ea, ea_mean, bo3, out);
}